// Round 4
// baseline (267.152 us; speedup 1.0000x reference)
//
#include <hip/hip_runtime.h>
#include <math.h>

#define BB 64
#define NN 1024
#define HID 64
#define STATE 32
#define NTYPES 10

typedef _Float16 f16;
typedef f16 f16x8 __attribute__((ext_vector_type(8)));
typedef float f32x4 __attribute__((ext_vector_type(4)));

#define MFMA16(a, b, c) __builtin_amdgcn_mfma_f32_16x16x32_f16(a, b, c, 0, 0, 0)

__device__ __forceinline__ float sigm(float x) { return 1.f / (1.f + expf(-x)); }

__device__ __forceinline__ f16x8 cvt8(float4 a, float4 b) {
    f16x8 r;
    r[0] = (f16)a.x; r[1] = (f16)a.y; r[2] = (f16)a.z; r[3] = (f16)a.w;
    r[4] = (f16)b.x; r[5] = (f16)b.y; r[6] = (f16)b.z; r[7] = (f16)b.w;
    return r;
}

// ---------------- misc: weight swizzle into B-frag layout + zero cnt/ctx
// prep segments: [0,4096): enc_w2 | [4096,8192): gnn_w L0 | [8192,12288): gnn_w L1
//                [12288,18432): head_w1 (K=96)
__global__ __launch_bounds__(256) void k_misc(
    const float* __restrict__ w2, const float* __restrict__ gw,
    const float* __restrict__ hw1, f16* __restrict__ out,
    int* __restrict__ cnt, float* __restrict__ ctx)
{
    int p = blockIdx.x * 256 + threadIdx.x;
    if (p < 18432) {
        const float* W; int K, pl;
        if (p < 12288) { int seg = p >> 12; pl = p & 4095; W = (seg == 0) ? w2 : gw + (seg - 1) * 4096; K = 64; }
        else { W = hw1; K = 96; pl = p - 12288; }
        int j = pl & 7, lane = (pl >> 3) & 63, nt = (pl >> 9) & 3, ch = pl >> 11;
        int k = ch * 32 + ((lane >> 4) << 3) + j;
        int o = nt * 16 + (lane & 15);
        out[p] = (f16)W[o * K + k];
        return;
    }
    int q = p - 18432;
    if (q < BB * NTYPES) cnt[q] = 0;
    else if (q < BB * NTYPES + BB * HID) ctx[q - BB * NTYPES] = 0.f;
}

// ---------------- encoder (MFMA) + fused bucketing
__global__ __launch_bounds__(256) void k_encoder(
    const float* __restrict__ feat,
    const float* __restrict__ w1, const float* __restrict__ b1,
    const f16* __restrict__ w2f, const float* __restrict__ b2,
    const int* __restrict__ types, int* __restrict__ idx, int* __restrict__ cnt,
    float* __restrict__ emb, float* __restrict__ nrm)
{
    __shared__ f16 w2s[4096];
    __shared__ f16 tmp[4][16 * 72];
    __shared__ float fbuf[4][48];
    int tid = threadIdx.x, wave = tid >> 6, lane = tid & 63;
    int l15 = lane & 15, quad = lane >> 4;
    // bucket: 64 rows of this block
    if (tid < 64) {
        int row = blockIdx.x * 64 + tid;
        int b = row >> 10;
        int t = types[row];
        int pos = atomicAdd(&cnt[b * NTYPES + t], 1);
        idx[(b * NTYPES + t) * NN + pos] = row & (NN - 1);
    }
    { const uint4* s = (const uint4*)w2f; uint4* d = (uint4*)w2s;
      for (int i = tid; i < 512; i += 256) d[i] = s[i]; }
    float w10 = w1[lane * 3], w11 = w1[lane * 3 + 1], w12 = w1[lane * 3 + 2], b1l = b1[lane];
    int tb = blockIdx.x * 64 + wave * 16;
    if (lane < 48) fbuf[wave][lane] = feat[tb * 3 + lane];
    __syncthreads();
    f16* tw = &tmp[wave][0];
#pragma unroll
    for (int r = 0; r < 16; ++r) {
        float x0 = fbuf[wave][r * 3], x1 = fbuf[wave][r * 3 + 1], x2 = fbuf[wave][r * 3 + 2];
        float hv = fmaxf(fmaf(w10, x0, fmaf(w11, x1, fmaf(w12, x2, b1l))), 0.f);
        tw[r * 72 + lane] = (f16)hv;
    }
    __builtin_amdgcn_sched_barrier(0);
    f16x8 a0 = *(const f16x8*)&tw[l15 * 72 + quad * 8];
    f16x8 a1 = *(const f16x8*)&tw[l15 * 72 + 32 + quad * 8];
    const f16x8* bf = (const f16x8*)w2s;
    f32x4 acc[4];
#pragma unroll
    for (int nt = 0; nt < 4; ++nt) {
        f32x4 c = {0.f, 0.f, 0.f, 0.f};
        c = MFMA16(a0, bf[(0 * 4 + nt) * 64 + lane], c);
        c = MFMA16(a1, bf[(1 * 4 + nt) * 64 + lane], c);
        acc[nt] = c;
    }
    float b2c[4];
#pragma unroll
    for (int nt = 0; nt < 4; ++nt) b2c[nt] = b2[nt * 16 + l15];
#pragma unroll
    for (int i = 0; i < 4; ++i) {
        float v[4]; float ss = 0.f;
#pragma unroll
        for (int nt = 0; nt < 4; ++nt) { v[nt] = acc[nt][i] + b2c[nt]; ss = fmaf(v[nt], v[nt], ss); }
        ss += __shfl_xor(ss, 1, 64); ss += __shfl_xor(ss, 2, 64);
        ss += __shfl_xor(ss, 4, 64); ss += __shfl_xor(ss, 8, 64);
        float rinv = 1.f / fmaxf(sqrtf(ss), 1e-12f);
        int grow = tb + quad * 4 + i;
#pragma unroll
        for (int nt = 0; nt < 4; ++nt) {
            emb[grow * 64 + nt * 16 + l15] = v[nt];
            nrm[grow * 64 + nt * 16 + l15] = v[nt] * rinv;
        }
    }
}

// ---------------- build M_j (d-sliced): block (b,j,s) computes M rows [16s,16s+16)
__global__ __launch_bounds__(256) void k_buildM(
    const int* __restrict__ idx, const int* __restrict__ cnt,
    const float* __restrict__ nrm, const float* __restrict__ h,
    f16* __restrict__ M)
{
    int blk = blockIdx.x;
    int s = blk & 3, bj = blk >> 2;
    int b = bj / NTYPES, j = bj % NTYPES;
    int c = cnt[b * NTYPES + j];
    const int* lst = idx + (b * NTYPES + j) * NN;
    int d = s * 16 + (threadIdx.x >> 4);
    int e4 = threadIdx.x & 15;
    const float* nb = nrm + (size_t)b * NN * HID;
    const float4* h4 = (const float4*)(h + (size_t)b * NN * HID);
    float acc[4] = {0.f, 0.f, 0.f, 0.f};
    int e = 0;
    for (; e + 8 <= c; e += 8) {
        int ms[8];
#pragma unroll
        for (int u = 0; u < 8; ++u) ms[u] = lst[e + u];
        float w[8]; float4 hh[8];
#pragma unroll
        for (int u = 0; u < 8; ++u) { w[u] = nb[ms[u] * 64 + d]; hh[u] = h4[ms[u] * 16 + e4]; }
#pragma unroll
        for (int u = 0; u < 8; ++u) {
            acc[0] = fmaf(w[u], hh[u].x, acc[0]);
            acc[1] = fmaf(w[u], hh[u].y, acc[1]);
            acc[2] = fmaf(w[u], hh[u].z, acc[2]);
            acc[3] = fmaf(w[u], hh[u].w, acc[3]);
        }
    }
    for (; e < c; ++e) {
        int m = lst[e];
        float w = nb[m * 64 + d];
        float4 hh = h4[m * 16 + e4];
        acc[0] = fmaf(w, hh.x, acc[0]);
        acc[1] = fmaf(w, hh.y, acc[1]);
        acc[2] = fmaf(w, hh.z, acc[2]);
        acc[3] = fmaf(w, hh.w, acc[3]);
    }
    union { f16 hv[4]; uint2 u; } pk;
#pragma unroll
    for (int q = 0; q < 4; ++q) pk.hv[q] = (f16)acc[q];
    f16* Mo = M + ((size_t)(b * NTYPES + j)) * 4096;
    *(uint2*)&Mo[d * 64 + e4 * 4] = pk.u;
}

// ---------------- buildCD: C_t = sum_j sg M_j ; D_t = C_t @ gw^T -> B-frag f16
__global__ __launch_bounds__(256) void k_buildCD(
    const float* __restrict__ cont, const f16* __restrict__ M,
    const f16* __restrict__ gwf, f16* __restrict__ Dfrag)
{
    __shared__ float Cs[64][68];
    __shared__ f16 gs[4096];
    int b = blockIdx.x / NTYPES, t = blockIdx.x % NTYPES;
    int tid = threadIdx.x, wave = tid >> 6, lane = tid & 63;
    int l15 = lane & 15, quad = lane >> 4;
    { const uint4* s2 = (const uint4*)gwf; uint4* d2 = (uint4*)gs;
      for (int i = tid; i < 512; i += 256) d2[i] = s2[i]; }
    float sg[NTYPES];
#pragma unroll
    for (int j = 0; j < NTYPES; ++j) sg[j] = sigm(cont[t * NTYPES + j]);
    const f16* Mb = M + (size_t)b * NTYPES * 4096;
    for (int p = tid; p < 4096; p += 256) {
        float a = 0.f;
#pragma unroll
        for (int j = 0; j < NTYPES; ++j) a = fmaf(sg[j], (float)Mb[j * 4096 + p], a);
        Cs[p >> 6][p & 63] = a;
    }
    __syncthreads();
    // wave handles d-tile = wave: rows 16*wave .. +15
    const float4* rc4 = (const float4*)&Cs[wave * 16 + l15][0];
    f16x8 a0 = cvt8(rc4[quad * 2], rc4[quad * 2 + 1]);
    f16x8 a1 = cvt8(rc4[8 + quad * 2], rc4[8 + quad * 2 + 1]);
    const f16x8* gbf = (const f16x8*)gs;
    f16* Do = Dfrag + (size_t)(b * NTYPES + t) * 4096;
#pragma unroll
    for (int nt = 0; nt < 4; ++nt) {
        f32x4 dd = {0.f, 0.f, 0.f, 0.f};
        dd = MFMA16(a0, gbf[(0 * 4 + nt) * 64 + lane], dd);
        dd = MFMA16(a1, gbf[(1 * 4 + nt) * 64 + lane], dd);
#pragma unroll
        for (int i = 0; i < 4; ++i) {
            int d = wave * 16 + quad * 4 + i;
            int pos = (((d >> 5) * 4 + nt) * 64 + ((d >> 3) & 3) * 16 + l15) * 8 + (d & 7);
            Do[pos] = (f16)dd[i];
        }
    }
}

// ---------------- GNN layer (sliced): out = relu(h@gw^T + nrm@D_t + gb)
__global__ __launch_bounds__(256) void k_gnn_layer(
    const int* __restrict__ idx, const int* __restrict__ cnt,
    const f16* __restrict__ Dfrag,
    const float* __restrict__ nrm, const float* __restrict__ h,
    const f16* __restrict__ gwf, const float* __restrict__ gb,
    float* __restrict__ hout, float* __restrict__ ctx)
{
    __shared__ f16 ds[4096];
    __shared__ f16 gs[4096];
    int blk = blockIdx.x;
    int s = blk & 3, bt = blk >> 2;
    int b = bt / NTYPES, t = bt % NTYPES;
    int c = cnt[b * NTYPES + t];
    if (c == 0) return;
    int tid = threadIdx.x, wave = tid >> 6, lane = tid & 63;
    int l15 = lane & 15, quad = lane >> 4;
    { const uint4* s1 = (const uint4*)(Dfrag + (size_t)bt * 4096);
      const uint4* s2 = (const uint4*)gwf;
      uint4* d1 = (uint4*)ds; uint4* d2 = (uint4*)gs;
      for (int i = tid; i < 512; i += 256) { d1[i] = s1[i]; d2[i] = s2[i]; } }
    float gbl[4];
#pragma unroll
    for (int nt = 0; nt < 4; ++nt) gbl[nt] = gb[nt * 16 + l15];
    const int* lst = idx + (b * NTYPES + t) * NN;
    const float* nb = nrm + (size_t)b * NN * HID;
    const float* hb = h + (size_t)b * NN * HID;
    float* hob = hout + (size_t)b * NN * HID;
    __syncthreads();
    const f16x8* dbf = (const f16x8*)ds;
    const f16x8* gbf = (const f16x8*)gs;
    float cacc[4] = {0.f, 0.f, 0.f, 0.f};
    for (int g = wave * 4 + s; g * 16 < c; g += 16) {
        int tb = g * 16;
        int rA = tb + l15; if (rA >= c) rA = c - 1;
        int mA = lst[rA];
        const float4* na = (const float4*)(nb + (size_t)mA * 64);
        const float4* ha = (const float4*)(hb + (size_t)mA * 64);
        f16x8 a0 = cvt8(na[quad * 2], na[quad * 2 + 1]);
        f16x8 a1 = cvt8(na[8 + quad * 2], na[8 + quad * 2 + 1]);
        f16x8 h0 = cvt8(ha[quad * 2], ha[quad * 2 + 1]);
        f16x8 h1 = cvt8(ha[8 + quad * 2], ha[8 + quad * 2 + 1]);
        f32x4 acc[4];
#pragma unroll
        for (int nt = 0; nt < 4; ++nt) {
            f32x4 cc = {0.f, 0.f, 0.f, 0.f};
            cc = MFMA16(a0, dbf[(0 * 4 + nt) * 64 + lane], cc);
            cc = MFMA16(a1, dbf[(1 * 4 + nt) * 64 + lane], cc);
            cc = MFMA16(h0, gbf[(0 * 4 + nt) * 64 + lane], cc);
            cc = MFMA16(h1, gbf[(1 * 4 + nt) * 64 + lane], cc);
            acc[nt] = cc;
        }
#pragma unroll
        for (int i = 0; i < 4; ++i) {
            int r = tb + quad * 4 + i;
            if (r < c) {
                int m = lst[r];
#pragma unroll
                for (int nt = 0; nt < 4; ++nt) {
                    float v = fmaxf(acc[nt][i] + gbl[nt], 0.f);
                    hob[(size_t)m * 64 + nt * 16 + l15] = v;
                    cacc[nt] += v;
                }
            }
        }
    }
    if (ctx) {
#pragma unroll
        for (int nt = 0; nt < 4; ++nt) {
            float sv = cacc[nt];
            sv += __shfl_xor(sv, 16, 64);
            sv += __shfl_xor(sv, 32, 64);
            if (quad == 0) atomicAdd(&ctx[b * HID + nt * 16 + l15], sv);
        }
    }
}

// ---------------- GRU from ctx sums -> new_state
__global__ __launch_bounds__(128) void k_gru(
    const float* __restrict__ ctx_sum, const float* __restrict__ prev,
    const float* __restrict__ w_ih, const float* __restrict__ w_hh,
    const float* __restrict__ b_ih, const float* __restrict__ b_hh,
    float* __restrict__ state_out)
{
    int b = blockIdx.x;
    int tid = threadIdx.x;
    __shared__ float cs[HID], ps[STATE], gis[96], ghs[96];
    if (tid < HID) cs[tid] = ctx_sum[b * HID + tid] * (1.f / NN);
    if (tid >= HID && tid < HID + STATE) ps[tid - HID] = prev[b * STATE + tid - HID];
    __syncthreads();
    if (tid < 96) {
        float gi = b_ih[tid];
#pragma unroll 8
        for (int k = 0; k < HID; ++k) gi = fmaf(w_ih[tid * HID + k], cs[k], gi);
        float gh = b_hh[tid];
#pragma unroll
        for (int k = 0; k < STATE; ++k) gh = fmaf(w_hh[tid * STATE + k], ps[k], gh);
        gis[tid] = gi; ghs[tid] = gh;
    }
    __syncthreads();
    if (tid < STATE) {
        float r = sigm(gis[tid] + ghs[tid]);
        float z = sigm(gis[32 + tid] + ghs[32 + tid]);
        float nn = tanhf(gis[64 + tid] + r * ghs[64 + tid]);
        float pv = ps[tid];
        state_out[b * STATE + tid] = (1.f - z) * nn + z * pv;
    }
}

// ---------------- head (MFMA): lat = relu([h2|st]@W1^T+b1)@w2 + b2
__global__ __launch_bounds__(256) void k_head(
    const float* __restrict__ h2, const float* __restrict__ state,
    const f16* __restrict__ hwf, const float* __restrict__ b1,
    const float* __restrict__ w2, const float* __restrict__ b2,
    float* __restrict__ lat)
{
    __shared__ f16 ws_[6144];
    int tid = threadIdx.x, wave = tid >> 6, lane = tid & 63;
    int l15 = lane & 15, quad = lane >> 4;
    int b = blockIdx.x >> 4;
    { const uint4* s = (const uint4*)hwf; uint4* d = (uint4*)ws_;
      for (int i = tid; i < 768; i += 256) d[i] = s[i]; }
    float b1c[4], w2c[4];
#pragma unroll
    for (int nt = 0; nt < 4; ++nt) { b1c[nt] = b1[nt * 16 + l15]; w2c[nt] = w2[nt * 16 + l15]; }
    float b2v = b2[0];
    __syncthreads();
    int tb = blockIdx.x * 64 + wave * 16;
    int grow = tb + l15;
    const float4* ha = (const float4*)(h2 + (size_t)grow * 64);
    f16x8 a0 = cvt8(ha[quad * 2], ha[quad * 2 + 1]);
    f16x8 a1 = cvt8(ha[8 + quad * 2], ha[8 + quad * 2 + 1]);
    const float4* sp = (const float4*)(state + b * STATE);
    f16x8 a2 = cvt8(sp[quad * 2], sp[quad * 2 + 1]);
    const f16x8* bf = (const f16x8*)ws_;
    f32x4 acc[4];
#pragma unroll
    for (int nt = 0; nt < 4; ++nt) {
        f32x4 cc = {0.f, 0.f, 0.f, 0.f};
        cc = MFMA16(a0, bf[(0 * 4 + nt) * 64 + lane], cc);
        cc = MFMA16(a1, bf[(1 * 4 + nt) * 64 + lane], cc);
        cc = MFMA16(a2, bf[(2 * 4 + nt) * 64 + lane], cc);
        acc[nt] = cc;
    }
#pragma unroll
    for (int i = 0; i < 4; ++i) {
        float s = 0.f;
#pragma unroll
        for (int nt = 0; nt < 4; ++nt) s = fmaf(fmaxf(acc[nt][i] + b1c[nt], 0.f), w2c[nt], s);
        s += __shfl_xor(s, 1, 64); s += __shfl_xor(s, 2, 64);
        s += __shfl_xor(s, 4, 64); s += __shfl_xor(s, 8, 64);
        if (l15 == 0) lat[tb + quad * 4 + i] = s + b2v;
    }
}

extern "C" void kernel_launch(void* const* d_in, const int* in_sizes, int n_in,
                              void* d_out, int out_size, void* d_ws, size_t ws_size,
                              hipStream_t stream) {
    const float* feat   = (const float*)d_in[0];
    const int*   types  = (const int*)d_in[1];
    const float* prev   = (const float*)d_in[2];
    const float* enc_w1 = (const float*)d_in[3];
    const float* enc_b1 = (const float*)d_in[4];
    const float* enc_w2 = (const float*)d_in[5];
    const float* enc_b2 = (const float*)d_in[6];
    const float* cont   = (const float*)d_in[7];
    const float* gnn_w  = (const float*)d_in[8];
    const float* gnn_b  = (const float*)d_in[9];
    const float* w_ih   = (const float*)d_in[10];
    const float* w_hh   = (const float*)d_in[11];
    const float* b_ih   = (const float*)d_in[12];
    const float* b_hh   = (const float*)d_in[13];
    const float* hw1    = (const float*)d_in[14];
    const float* hb1    = (const float*)d_in[15];
    const float* hw2    = (const float*)d_in[16];
    const float* hb2    = (const float*)d_in[17];
    float* out = (float*)d_out;

    float* ws  = (float*)d_ws;
    float* h0  = ws;                       // 4194304 floats (emb / h2)
    float* h1  = ws + 4194304;             // 4194304 floats
    float* nrm = ws + 8388608;             // 4194304 floats
    int*   idx = (int*)(ws + 12582912);    // 655360 ints
    int*   cnt = idx + BB * NTYPES * NN;   // 640 ints
    f16*   M     = (f16*)(ws + 12582912 + 656000);              // 2621440 halfs
    f16*   Dfrag = (f16*)(ws + 12582912 + 656000 + 1310720);    // 2621440 halfs
    f16*   wfrag = (f16*)(ws + 12582912 + 656000 + 2621440);    // 18432 halfs
    float* ctx   = ws + 12582912 + 656000 + 2621440 + 9216;     // 4096 floats
    f16*   w2f  = wfrag;
    f16*   gw0f = wfrag + 4096;
    f16*   gw1f = wfrag + 8192;
    f16*   hwf  = wfrag + 12288;

    k_misc<<<91, 256, 0, stream>>>(enc_w2, gnn_w, hw1, wfrag, cnt, ctx);
    k_encoder<<<BB * NN / 64, 256, 0, stream>>>(feat, enc_w1, enc_b1, w2f, enc_b2,
                                                types, idx, cnt, h0, nrm);
    // layer 0: h = h0(emb) -> h1
    k_buildM<<<BB * NTYPES * 4, 256, 0, stream>>>(idx, cnt, nrm, h0, M);
    k_buildCD<<<BB * NTYPES, 256, 0, stream>>>(cont, M, gw0f, Dfrag);
    k_gnn_layer<<<BB * NTYPES * 4, 256, 0, stream>>>(idx, cnt, Dfrag, nrm, h0, gw0f, gnn_b, h1, nullptr);
    // layer 1: h = h1 -> h2 (in h0 region), fused ctx column-sum accumulation
    k_buildM<<<BB * NTYPES * 4, 256, 0, stream>>>(idx, cnt, nrm, h1, M);
    k_buildCD<<<BB * NTYPES, 256, 0, stream>>>(cont, M, gw1f, Dfrag);
    k_gnn_layer<<<BB * NTYPES * 4, 256, 0, stream>>>(idx, cnt, Dfrag, nrm, h1, gw1f, gnn_b + HID, h0, ctx);
    // GRU -> new_state (tail of d_out)
    k_gru<<<BB, 128, 0, stream>>>(ctx, prev, w_ih, w_hh, b_ih, b_hh, out + BB * NN);
    // head
    k_head<<<BB * NN / 64, 256, 0, stream>>>(h0, out + BB * NN, hwf, hb1, hw2, hb2, out);
}